// Round 10
// baseline (155.129 us; speedup 1.0000x reference)
//
#include <hip/hip_runtime.h>
#include <hip/hip_bf16.h>

typedef float f32x4 __attribute__((ext_vector_type(4)));
typedef __bf16 bf16x8 __attribute__((ext_vector_type(8)));
typedef unsigned short u16x8 __attribute__((ext_vector_type(8)));
typedef int i32x4 __attribute__((ext_vector_type(4)));

#define NEG_BIG_F (-1000000000.0f)
#define SCALE_F 0.044194173824159216f

__device__ __forceinline__ unsigned short f2bf(float f) {
  unsigned int u = __float_as_uint(f);
  u += 0x7FFFu + ((u >> 16) & 1u);   // round-to-nearest-even
  return (unsigned short)(u >> 16);
}

__device__ __forceinline__ float bf2f(unsigned short h) {
  return __uint_as_float((unsigned int)h << 16);
}

__device__ __forceinline__ u16x8 cvt8(f32x4 a, f32x4 b) {
  u16x8 r;
  r[0] = f2bf(a[0]); r[1] = f2bf(a[1]); r[2] = f2bf(a[2]); r[3] = f2bf(a[3]);
  r[4] = f2bf(b[0]); r[5] = f2bf(b[1]); r[6] = f2bf(b[2]); r[7] = f2bf(b[3]);
  return r;
}

__device__ __forceinline__ bf16x8 u2b(u16x8 u) {
  union { u16x8 u; bf16x8 b; } c; c.u = u; return c.b;
}

__device__ __forceinline__ void gload16(const void* g, char* l) {
  __builtin_amdgcn_global_load_lds(
      (const __attribute__((address_space(1))) unsigned int*)g,
      (__attribute__((address_space(3))) unsigned int*)l, 16, 0, 0);
}

// ---------------------------------------------------------------------------
// cvtW: three 512x512 fp32 weight matrices -> bf16
// ---------------------------------------------------------------------------
__global__ __launch_bounds__(256) void cvtW(
    const float* __restrict__ w0, const float* __restrict__ w1,
    const float* __restrict__ w2, unsigned short* __restrict__ out)
{
  const float* src = blockIdx.z == 0 ? w0 : (blockIdx.z == 1 ? w1 : w2);
  unsigned short* dst = out + (size_t)blockIdx.z * 262144;
  const int i = (blockIdx.x * 256 + threadIdx.x) * 8;
  f32x4 a = *(const f32x4*)(src + i);
  f32x4 b = *(const f32x4*)(src + i + 4);
  *(u16x8*)&dst[i] = cvt8(a, b);
}

// ---------------------------------------------------------------------------
// projqk: z=bid>>8: 0 qb=Q·WQ^T, 1 kb=K·WK^T. 128x256 tile, BK=32, 512 thr
// (8 waves 2Mx4N, wave tile 64x64). PURE global_load_lds pipeline (score256's
// proven schedule, vmcnt(4) steady): A = fp32 into swizzled f32 LDS tile
// (slot^(row&7), inverse-swz source), converted bf16 AT FRAGMENT READ;
// B = bf16 (slot^((row>>1)&3)). No reg staging, no ds_write. LDS 64 KB.
// ---------------------------------------------------------------------------
__global__ __launch_bounds__(512, 2) void projqk(
    const float* __restrict__ Q, const float* __restrict__ Kx,
    const unsigned short* __restrict__ wb,
    unsigned short* __restrict__ qb, unsigned short* __restrict__ kb)
{
  __shared__ __align__(16) float          Af[2][128][32];  // 32 KB
  __shared__ __align__(16) unsigned short Bs[2][256][32];  // 32 KB

  const int bid = blockIdx.x;
  const int z = bid >> 8, rem = bid & 255;
  const float* X = z ? Kx : Q;
  const unsigned short* W = wb + (size_t)z * 262144;
  unsigned short* Y = z ? kb : qb;
  const int m0 = (rem >> 1) * 128, n0 = (rem & 1) * 256;
  const int tid = threadIdx.x;
  const int lane = tid & 63, wave = tid >> 6;
  const int wr = (wave >> 2) * 64, wc = (wave & 3) * 64;
  const int fr = lane & 15, fq = lane >> 4;

  f32x4 acc[4][4] = {};

  // A: 1024 16B-chunks (8/row of 32 f32), 2/thread. row=c>>3, slot=c&7.
  const float* gA[2]; char* lA[2];
  #pragma unroll
  for (int i = 0; i < 2; i++) {
    const int c = tid + 512 * i, row = c >> 3, slot = c & 7;
    gA[i] = X + (size_t)(m0 + row) * 512 + (slot ^ (row & 7)) * 4;
    lA[i] = (char*)&Af[0][0][0] + c * 16;
  }
  // B: 1024 16B-chunks (4/row of 32 bf16), 2/thread. row=c>>2, slot=c&3.
  const unsigned short* gB[2]; char* lB[2];
  #pragma unroll
  for (int i = 0; i < 2; i++) {
    const int c = tid + 512 * i, row = c >> 2, slot = c & 3;
    gB[i] = W + (size_t)(n0 + row) * 512 + (slot ^ ((row >> 1) & 3)) * 8;
    lB[i] = (char*)&Bs[0][0][0] + c * 16;
  }

  #pragma unroll
  for (int i = 0; i < 2; i++) { gload16(gA[i], lA[i]); gload16(gB[i], lB[i]); }

  int cur = 0;
  for (int kt = 0; kt < 512; kt += 32) {
    const int nb = cur ^ 1;
    if (kt < 480) {
      #pragma unroll
      for (int i = 0; i < 2; i++) {
        gload16(gA[i] + kt + 32, lA[i] + nb * 16384);
        gload16(gB[i] + kt + 32, lB[i] + nb * 16384);
      }
      asm volatile("s_waitcnt vmcnt(4) lgkmcnt(0)" ::: "memory");
    } else {
      asm volatile("s_waitcnt vmcnt(0) lgkmcnt(0)" ::: "memory");
    }
    __builtin_amdgcn_sched_barrier(0);
    __builtin_amdgcn_s_barrier();

    bf16x8 av[4], bv[4];
    #pragma unroll
    for (int nf = 0; nf < 4; nf++) {
      const int br = wc + nf * 16 + fr;
      bv[nf] = *(const bf16x8*)&Bs[cur][br][(fq ^ ((br >> 1) & 3)) * 8];
    }
    #pragma unroll
    for (int mf = 0; mf < 4; mf++) {
      const int ar = wr + mf * 16 + fr;
      f32x4 lo = *(const f32x4*)&Af[cur][ar][((fq * 2)     ^ (ar & 7)) * 4];
      f32x4 hi = *(const f32x4*)&Af[cur][ar][((fq * 2 + 1) ^ (ar & 7)) * 4];
      av[mf] = u2b(cvt8(lo, hi));
    }
    #pragma unroll
    for (int mf = 0; mf < 4; mf++)
      #pragma unroll
      for (int nf = 0; nf < 4; nf++)
        acc[mf][nf] = __builtin_amdgcn_mfma_f32_16x16x32_bf16(av[mf], bv[nf], acc[mf][nf], 0, 0, 0);
    __builtin_amdgcn_s_barrier();
    cur = nb;
  }

  #pragma unroll
  for (int mf = 0; mf < 4; mf++)
    #pragma unroll
    for (int nf = 0; nf < 4; nf++)
      #pragma unroll
      for (int rr = 0; rr < 4; rr++) {
        const int m = m0 + wr + mf * 16 + fq * 4 + rr;
        const int n = n0 + wc + nf * 16 + fr;
        Y[(size_t)m * 512 + n] = f2bf(acc[mf][nf][rr]);
      }
}

// ---------------------------------------------------------------------------
// projv: vt[b][e][s] = sum_d WV[e][d]*V[b][s][d]. 128(e)x256(s), BK=32,
// 512 thr. A = wv bf16 gload (1 chunk/thr); B = V fp32 gload into swizzled
// f32 tile (4 chunks/thr), cvt at read. vmcnt(5) steady. LDS 80 KB.
// ---------------------------------------------------------------------------
__global__ __launch_bounds__(512, 2) void projv(
    const float* __restrict__ V, const unsigned short* __restrict__ wv,
    unsigned short* __restrict__ vt)
{
  __shared__ __align__(16) unsigned short As[2][128][32];  // 16 KB
  __shared__ __align__(16) float          Bf[2][256][32];  // 64 KB

  const int bid = blockIdx.x;
  const int m0 = (bid & 3) * 128, n0 = ((bid >> 2) & 3) * 256, b = bid >> 4;
  const int tid = threadIdx.x;
  const int lane = tid & 63, wave = tid >> 6;
  const int wr = (wave >> 2) * 64, wc = (wave & 3) * 64;
  const int fr = lane & 15, fq = lane >> 4;

  f32x4 acc[4][4] = {};

  // A: 512 chunks, 1/thread. row=tid>>2, slot=tid&3.
  const int arw = tid >> 2, asl = tid & 3;
  const unsigned short* gA = wv + (size_t)(m0 + arw) * 512 + (asl ^ ((arw >> 1) & 3)) * 8;
  char* lA = (char*)&As[0][0][0] + tid * 16;
  // B: 2048 chunks (8/row of 32 f32), 4/thread. row=c>>3, slot=c&7.
  const float* gB[4]; char* lB[4];
  #pragma unroll
  for (int i = 0; i < 4; i++) {
    const int c = tid + 512 * i, row = c >> 3, slot = c & 7;
    gB[i] = V + ((size_t)b * 1024 + n0 + row) * 512 + (slot ^ (row & 7)) * 4;
    lB[i] = (char*)&Bf[0][0][0] + c * 16;
  }

  gload16(gA, lA);
  #pragma unroll
  for (int i = 0; i < 4; i++) gload16(gB[i], lB[i]);

  int cur = 0;
  for (int kt = 0; kt < 512; kt += 32) {
    const int nb = cur ^ 1;
    if (kt < 480) {
      gload16(gA + kt + 32, lA + nb * 8192);
      #pragma unroll
      for (int i = 0; i < 4; i++) gload16(gB[i] + kt + 32, lB[i] + nb * 32768);
      asm volatile("s_waitcnt vmcnt(5) lgkmcnt(0)" ::: "memory");
    } else {
      asm volatile("s_waitcnt vmcnt(0) lgkmcnt(0)" ::: "memory");
    }
    __builtin_amdgcn_sched_barrier(0);
    __builtin_amdgcn_s_barrier();

    bf16x8 av[4], bv[4];
    #pragma unroll
    for (int mf = 0; mf < 4; mf++) {
      const int ar = wr + mf * 16 + fr;
      av[mf] = *(const bf16x8*)&As[cur][ar][(fq ^ ((ar >> 1) & 3)) * 8];
    }
    #pragma unroll
    for (int nf = 0; nf < 4; nf++) {
      const int br = wc + nf * 16 + fr;
      f32x4 lo = *(const f32x4*)&Bf[cur][br][((fq * 2)     ^ (br & 7)) * 4];
      f32x4 hi = *(const f32x4*)&Bf[cur][br][((fq * 2 + 1) ^ (br & 7)) * 4];
      bv[nf] = u2b(cvt8(lo, hi));
    }
    #pragma unroll
    for (int mf = 0; mf < 4; mf++)
      #pragma unroll
      for (int nf = 0; nf < 4; nf++)
        acc[mf][nf] = __builtin_amdgcn_mfma_f32_16x16x32_bf16(av[mf], bv[nf], acc[mf][nf], 0, 0, 0);
    __builtin_amdgcn_s_barrier();
    cur = nb;
  }

  #pragma unroll
  for (int mf = 0; mf < 4; mf++)
    #pragma unroll
    for (int nf = 0; nf < 4; nf++)
      #pragma unroll
      for (int rr = 0; rr < 4; rr++) {
        const int e = m0 + wr + mf * 16 + fq * 4 + rr;
        const int s = n0 + wc + nf * 16 + fr;
        vt[((size_t)b * 512 + e) * 1024 + s] = f2bf(acc[mf][nf][rr]);
      }
}

// ---------------------------------------------------------------------------
// score256: s = (q k^T)/sqrt(512). Writes P''[b][m][k] = mask ? bf16(exp(s))
// : 0 + per-row partial exp-sums. (unchanged — proven)
// ---------------------------------------------------------------------------
__global__ __launch_bounds__(512, 2) void score256(
    const unsigned short* __restrict__ qb, const unsigned short* __restrict__ kb,
    const int* __restrict__ mask,
    unsigned short* __restrict__ P, float* __restrict__ partial)
{
  __shared__ __align__(16) unsigned short As[2][256][32];
  __shared__ __align__(16) unsigned short Bs[2][256][32];

  const int tid = threadIdx.x, bz = blockIdx.z;
  const int m0 = blockIdx.x * 256, n0 = blockIdx.y * 256;
  const int lane = tid & 63, wave = tid >> 6;
  const int wr = (wave >> 2) * 128, wc = (wave & 3) * 64;
  const int fr = lane & 15, fq = lane >> 4;

  f32x4 acc[8][4] = {};

  const unsigned short* gA[2]; char* lA[2];
  const unsigned short* gB[2]; char* lB[2];
  #pragma unroll
  for (int i = 0; i < 2; i++) {
    const int c = tid + 512 * i, row = c >> 2, slot = c & 3;
    const int sw = (slot ^ ((row >> 1) & 3)) * 8;
    gA[i] = qb + ((size_t)bz * 1024 + m0 + row) * 512 + sw;
    gB[i] = kb + ((size_t)bz * 1024 + n0 + row) * 512 + sw;
    lA[i] = (char*)&As[0][0][0] + c * 16;
    lB[i] = (char*)&Bs[0][0][0] + c * 16;
  }

  #pragma unroll
  for (int i = 0; i < 2; i++) { gload16(gA[i], lA[i]); gload16(gB[i], lB[i]); }

  int cur = 0;
  for (int kt = 0; kt < 512; kt += 32) {
    const int nb = cur ^ 1;
    if (kt < 480) {
      #pragma unroll
      for (int i = 0; i < 2; i++) {
        gload16(gA[i] + kt + 32, lA[i] + nb * 16384);
        gload16(gB[i] + kt + 32, lB[i] + nb * 16384);
      }
      asm volatile("s_waitcnt vmcnt(4) lgkmcnt(0)" ::: "memory");
    } else {
      asm volatile("s_waitcnt vmcnt(0) lgkmcnt(0)" ::: "memory");
    }
    __builtin_amdgcn_sched_barrier(0);
    __builtin_amdgcn_s_barrier();

    bf16x8 bv[4];
    #pragma unroll
    for (int nf = 0; nf < 4; nf++) {
      const int br = wc + nf * 16 + fr;
      bv[nf] = *(const bf16x8*)&Bs[cur][br][(fq ^ ((br >> 1) & 3)) * 8];
    }
    #pragma unroll
    for (int mf = 0; mf < 8; mf++) {
      const int ar = wr + mf * 16 + fr;
      bf16x8 av = *(const bf16x8*)&As[cur][ar][(fq ^ ((ar >> 1) & 3)) * 8];
      #pragma unroll
      for (int nf = 0; nf < 4; nf++)
        acc[mf][nf] = __builtin_amdgcn_mfma_f32_16x16x32_bf16(av, bv[nf], acc[mf][nf], 0, 0, 0);
    }
    __builtin_amdgcn_s_barrier();
    cur = nb;
  }

  int mcol[4];
  #pragma unroll
  for (int nf = 0; nf < 4; nf++)
    mcol[nf] = mask[bz * 1024 + n0 + wc + nf * 16 + fr];

  unsigned short* Pb = P + ((size_t)bz << 20);
  const int slot = blockIdx.y * 4 + (wave & 3);
  #pragma unroll
  for (int mf = 0; mf < 8; mf++) {
    #pragma unroll
    for (int rr = 0; rr < 4; rr++) {
      const int m = m0 + wr + mf * 16 + fq * 4 + rr;
      float e = 0.f;
      #pragma unroll
      for (int nf = 0; nf < 4; nf++) {
        const float ev = __expf(acc[mf][nf][rr] * SCALE_F);
        e += ev;
        Pb[(size_t)m * 1024 + n0 + wc + nf * 16 + fr] =
            mcol[nf] ? f2bf(ev) : (unsigned short)0;
      }
      e += __shfl_xor(e, 1); e += __shfl_xor(e, 2);
      e += __shfl_xor(e, 4); e += __shfl_xor(e, 8);
      if (fr == 0)
        partial[(size_t)slot * 16384 + bz * 1024 + m] = e;
    }
  }
}

// ---------------------------------------------------------------------------
// mv_attn: blocks 0-2047 = mvsum; 2048-10239 = attn_write (inv from partial).
// (unchanged)
// ---------------------------------------------------------------------------
__global__ __launch_bounds__(256) void mv_attn(
    const unsigned short* __restrict__ vt, const unsigned short* __restrict__ P,
    const float* __restrict__ partial, const int* __restrict__ mask,
    float* __restrict__ mvsum, float* __restrict__ attn)
{
  const int bid = blockIdx.x;
  const int tid = threadIdx.x;
  if (bid < 2048) {
    const int row = bid * 4 + (tid >> 6);   // 0..8191 = b*512+e
    const int b = row >> 9;
    const int lane = tid & 63;
    const unsigned short* vr = vt + (size_t)row * 1024 + lane * 16;
    const int* mr = mask + b * 1024 + lane * 16;
    u16x8 v0 = *(const u16x8*)(vr);
    u16x8 v1 = *(const u16x8*)(vr + 8);
    float s = 0.f;
    #pragma unroll
    for (int j = 0; j < 8; j++) {
      if (!mr[j])     s += bf2f(v0[j]);
      if (!mr[8 + j]) s += bf2f(v1[j]);
    }
    #pragma unroll
    for (int o = 32; o > 0; o >>= 1) s += __shfl_xor(s, o);
    if (lane == 0) mvsum[row] = s;
  } else {
    const int ab = bid - 2048;              // 0..8191, covers 2 q-rows each
    __shared__ float s_inv[2];
    const int row0 = ab * 2;
    if (tid < 2) {
      float s = 0.f;
      #pragma unroll
      for (int p = 0; p < 16; p++) s += partial[(size_t)p * 16384 + row0 + tid];
      s_inv[tid] = 1.0f / s;
    }
    __syncthreads();
    const size_t base = (size_t)ab * 2048 + tid * 8;
    const int b = (int)(base >> 20);
    const int k0 = (int)(base & 1023);
    const u16x8 p8 = *(const u16x8*)(P + base);
    const float iv = s_inv[tid >> 7];
    const int* mr = mask + b * 1024 + k0;
    const i32x4 ma = *(const i32x4*)(mr);
    const i32x4 mb = *(const i32x4*)(mr + 4);
    f32x4 o0, o1;
    o0[0] = ma[0] ? bf2f(p8[0]) * iv : NEG_BIG_F;
    o0[1] = ma[1] ? bf2f(p8[1]) * iv : NEG_BIG_F;
    o0[2] = ma[2] ? bf2f(p8[2]) * iv : NEG_BIG_F;
    o0[3] = ma[3] ? bf2f(p8[3]) * iv : NEG_BIG_F;
    o1[0] = mb[0] ? bf2f(p8[4]) * iv : NEG_BIG_F;
    o1[1] = mb[1] ? bf2f(p8[5]) * iv : NEG_BIG_F;
    o1[2] = mb[2] ? bf2f(p8[6]) * iv : NEG_BIG_F;
    o1[3] = mb[3] ? bf2f(p8[7]) * iv : NEG_BIG_F;
    *(f32x4*)(attn + base) = o0;
    *(f32x4*)(attn + base + 4) = o1;
  }
}

// ---------------------------------------------------------------------------
// pv_gemm: out[b][m][e] = inv[m]*(P''·vt^T) - 1e9*mvsum[b][e]. (unchanged)
// ---------------------------------------------------------------------------
__global__ __launch_bounds__(512) void pv_gemm(
    const unsigned short* __restrict__ P, const unsigned short* __restrict__ vt,
    const float* __restrict__ partial, const float* __restrict__ mvsum,
    float* __restrict__ out)
{
  __shared__ __align__(16) unsigned short As[2][64][32];   // 8 KB
  __shared__ __align__(16) unsigned short Bs[2][512][32];  // 64 KB
  __shared__ float inv_l[64];

  const int tid = threadIdx.x;
  const int bz = blockIdx.z, m0 = blockIdx.x * 64;
  const int lane = tid & 63, wave = tid >> 6;
  const int n0 = wave * 64;
  const int fr = lane & 15, fq = lane >> 4;

  f32x4 acc[4][4] = {};

  if (tid < 64) {
    float s = 0.f;
    #pragma unroll
    for (int p = 0; p < 16; p++) s += partial[(size_t)p * 16384 + bz * 1024 + m0 + tid];
    inv_l[tid] = 1.0f / s;
  }

  const unsigned short* gA = nullptr; char* lA = nullptr;
  if (tid < 256) {
    const int row = tid >> 2, slot = tid & 3;
    gA = P + ((size_t)bz << 20) + (size_t)(m0 + row) * 1024 + (slot ^ ((row >> 1) & 3)) * 8;
    lA = (char*)&As[0][0][0] + tid * 16;
  }
  const unsigned short* gB[4]; char* lB[4];
  #pragma unroll
  for (int i = 0; i < 4; i++) {
    const int c = tid + 512 * i, row = c >> 2, slot = c & 3;
    gB[i] = vt + ((size_t)bz * 512 + row) * 1024 + (slot ^ ((row >> 1) & 3)) * 8;
    lB[i] = (char*)&Bs[0][0][0] + c * 16;
  }

  if (tid < 256) gload16(gA, lA);
  #pragma unroll
  for (int i = 0; i < 4; i++) gload16(gB[i], lB[i]);

  int cur = 0;
  for (int t = 0; t < 32; t++) {
    const int nb = cur ^ 1;
    const int kt = t * 32;
    if (t < 31) {
      if (tid < 256) gload16(gA + kt + 32, lA + nb * 4096);
      #pragma unroll
      for (int i = 0; i < 4; i++) gload16(gB[i] + kt + 32, lB[i] + nb * 32768);
      if (wave < 4) asm volatile("s_waitcnt vmcnt(5) lgkmcnt(0)" ::: "memory");
      else          asm volatile("s_waitcnt vmcnt(4) lgkmcnt(0)" ::: "memory");
    } else {
      asm volatile("s_waitcnt vmcnt(0) lgkmcnt(0)" ::: "memory");
    }
    __builtin_amdgcn_sched_barrier(0);
    __builtin_amdgcn_s_barrier();

    bf16x8 af[4], bv[4];
    #pragma unroll
    for (int mf = 0; mf < 4; mf++) {
      const int ar = mf * 16 + fr;
      af[mf] = *(const bf16x8*)&As[cur][ar][(fq ^ ((ar >> 1) & 3)) * 8];
    }
    #pragma unroll
    for (int nf = 0; nf < 4; nf++) {
      const int br = n0 + nf * 16 + fr;
      bv[nf] = *(const bf16x8*)&Bs[cur][br][(fq ^ ((br >> 1) & 3)) * 8];
    }
    #pragma unroll
    for (int mf = 0; mf < 4; mf++)
      #pragma unroll
      for (int nf = 0; nf < 4; nf++)
        acc[mf][nf] = __builtin_amdgcn_mfma_f32_16x16x32_bf16(af[mf], bv[nf], acc[mf][nf], 0, 0, 0);
    __builtin_amdgcn_s_barrier();
    cur = nb;
  }

  float mvv[4];
  #pragma unroll
  for (int nf = 0; nf < 4; nf++)
    mvv[nf] = mvsum[bz * 512 + n0 + nf * 16 + fr];
  #pragma unroll
  for (int mf = 0; mf < 4; mf++)
    #pragma unroll
    for (int rr = 0; rr < 4; rr++) {
      const int m = m0 + mf * 16 + fq * 4 + rr;
      const float iv = inv_l[mf * 16 + fq * 4 + rr];
      #pragma unroll
      for (int nf = 0; nf < 4; nf++)
        out[((size_t)bz * 1024 + m) * 512 + n0 + nf * 16 + fr] =
            iv * acc[mf][nf][rr] + NEG_BIG_F * mvv[nf];
    }
}

// ---------------------------------------------------------------------------
extern "C" void kernel_launch(void* const* d_in, const int* in_sizes, int n_in,
                              void* d_out, int out_size, void* d_ws, size_t ws_size,
                              hipStream_t stream)
{
  const float* Q  = (const float*)d_in[0];
  const float* Kx = (const float*)d_in[1];
  const float* V  = (const float*)d_in[2];
  const float* WQ = (const float*)d_in[3];
  const float* WK = (const float*)d_in[4];
  const float* WV = (const float*)d_in[5];
  const int* mask = (const int*)d_in[6];

  const int B = 16, S = 1024, D = 512;
  float* out_f  = (float*)d_out;                      // B*S*D fp32 (final out)
  float* attn_f = out_f + (size_t)B * S * D;          // B*S*S fp32 (final attn)
  unsigned short* Pbuf = (unsigned short*)d_out;      // P'' bf16 aliases out region

  // ws: qb | kb | vt (8.39M ushorts each) | wb (0.79M) | partial | mvsum
  unsigned short* qb = (unsigned short*)d_ws;
  unsigned short* kb = qb + (size_t)B * S * D;
  unsigned short* vt = kb + (size_t)B * S * D;
  unsigned short* wb = vt + (size_t)B * S * D;
  float* partial = (float*)(wb + 786432);             // 16 x 16384 f32
  float* mvsum = partial + 262144;                    // 16 x 512 f32

  cvtW<<<dim3(128, 1, 3), 256, 0, stream>>>(WQ, WK, WV, wb);
  projqk<<<dim3(512), 512, 0, stream>>>(Q, Kx, wb, qb, kb);
  projv<<<dim3(256), 512, 0, stream>>>(V, wb + 524288, vt);
  score256<<<dim3(4, 4, 16), 512, 0, stream>>>(qb, kb, mask, Pbuf, partial);
  mv_attn<<<dim3(10240), 256, 0, stream>>>(vt, Pbuf, partial, mask, mvsum, attn_f);
  pv_gemm<<<dim3(16, 1, 16), 512, 0, stream>>>(Pbuf, vt, partial, mvsum, out_f);
}

// Round 11
// 143.328 us; speedup vs baseline: 1.0823x; 1.0823x over previous
//
#include <hip/hip_runtime.h>
#include <hip/hip_bf16.h>

typedef float f32x4 __attribute__((ext_vector_type(4)));
typedef __bf16 bf16x8 __attribute__((ext_vector_type(8)));
typedef unsigned short u16x8 __attribute__((ext_vector_type(8)));
typedef unsigned short u16x4 __attribute__((ext_vector_type(4)));
typedef int i32x4 __attribute__((ext_vector_type(4)));

#define NEG_BIG_F (-1000000000.0f)
#define SCALE_F 0.044194173824159216f

__device__ __forceinline__ unsigned short f2bf(float f) {
  unsigned int u = __float_as_uint(f);
  u += 0x7FFFu + ((u >> 16) & 1u);   // round-to-nearest-even
  return (unsigned short)(u >> 16);
}

__device__ __forceinline__ float bf2f(unsigned short h) {
  return __uint_as_float((unsigned int)h << 16);
}

__device__ __forceinline__ u16x8 cvt8(f32x4 a, f32x4 b) {
  u16x8 r;
  r[0] = f2bf(a[0]); r[1] = f2bf(a[1]); r[2] = f2bf(a[2]); r[3] = f2bf(a[3]);
  r[4] = f2bf(b[0]); r[5] = f2bf(b[1]); r[6] = f2bf(b[2]); r[7] = f2bf(b[3]);
  return r;
}

__device__ __forceinline__ void gload16(const void* g, char* l) {
  __builtin_amdgcn_global_load_lds(
      (const __attribute__((address_space(1))) unsigned int*)g,
      (__attribute__((address_space(3))) unsigned int*)l, 16, 0, 0);
}

// ---------------------------------------------------------------------------
// cvtW: three 512x512 fp32 weight matrices -> bf16
// ---------------------------------------------------------------------------
__global__ __launch_bounds__(256) void cvtW(
    const float* __restrict__ w0, const float* __restrict__ w1,
    const float* __restrict__ w2, unsigned short* __restrict__ out)
{
  const float* src = blockIdx.z == 0 ? w0 : (blockIdx.z == 1 ? w1 : w2);
  unsigned short* dst = out + (size_t)blockIdx.z * 262144;
  const int i = (blockIdx.x * 256 + threadIdx.x) * 8;
  f32x4 a = *(const f32x4*)(src + i);
  f32x4 b = *(const f32x4*)(src + i + 4);
  *(u16x8*)&dst[i] = cvt8(a, b);
}

// ---------------------------------------------------------------------------
// proj_all (R9 verbatim, best measured): blocks 0-255 projqk (256x256),
// 256-511 projv (128x256). Counted-vmcnt two-barrier loop; fp32 operand
// reg-staged 2 tiles ahead.
// ---------------------------------------------------------------------------
__global__ __launch_bounds__(512, 2) void proj_all(
    const float* __restrict__ Q, const float* __restrict__ Kx,
    const float* __restrict__ V, const unsigned short* __restrict__ wb,
    unsigned short* __restrict__ qb, unsigned short* __restrict__ kb,
    unsigned short* __restrict__ vt)
{
  __shared__ __align__(16) unsigned short lds[32768];   // 64 KB pool

  const int bid = blockIdx.x;
  const int tid = threadIdx.x;
  const int lane = tid & 63, wave = tid >> 6;
  const int fr = lane & 15, fq = lane >> 4;

  if (bid < 256) {
    const int z = bid >> 7, rem = bid & 127;
    const float* X = z ? Kx : Q;
    const unsigned short* W = wb + (size_t)z * 262144;
    unsigned short* Y = z ? kb : qb;
    const int m0 = (rem & 63) * 256, n0 = (rem >> 6) * 256;
    const int wr = (wave >> 2) * 128, wc = (wave & 3) * 64;

    unsigned short (*As)[256][32] = (unsigned short (*)[256][32])lds;
    unsigned short (*Bs)[256][32] = (unsigned short (*)[256][32])(lds + 16384);

    f32x4 acc[8][4] = {};

    int arow_s[2], aswz_s[2];
    const float* gAs[2];
    #pragma unroll
    for (int i = 0; i < 2; i++) {
      const int c = tid + 512 * i;
      arow_s[i] = c >> 2;
      aswz_s[i] = ((c & 3) ^ ((arow_s[i] >> 1) & 3)) * 8;
      gAs[i] = X + (size_t)(m0 + arow_s[i]) * 512 + (c & 3) * 8;
    }
    const unsigned short* gB[2]; char* lB[2];
    #pragma unroll
    for (int i = 0; i < 2; i++) {
      const int c = tid + 512 * i, row = c >> 2, slot = c & 3;
      gB[i] = W + (size_t)(n0 + row) * 512 + (slot ^ ((row >> 1) & 3)) * 8;
      lB[i] = (char*)(lds + 16384) + c * 16;
    }

    f32x4 pa[2][2][2];
    #pragma unroll
    for (int i = 0; i < 2; i++) {
      pa[0][i][0] = *(const f32x4*)(gAs[i]);
      pa[0][i][1] = *(const f32x4*)(gAs[i] + 4);
      pa[1][i][0] = *(const f32x4*)(gAs[i] + 32);
      pa[1][i][1] = *(const f32x4*)(gAs[i] + 36);
    }
    #pragma unroll
    for (int i = 0; i < 2; i++) gload16(gB[i], lB[i]);
    #pragma unroll
    for (int i = 0; i < 2; i++)
      *(u16x8*)&As[0][arow_s[i]][aswz_s[i]] = cvt8(pa[0][i][0], pa[0][i][1]);

    #pragma unroll
    for (int t = 0; t < 16; t++) {
      const int cur = t & 1, nxt = cur ^ 1;
      const int kt = t * 32;
      if (t < 15) {
        #pragma unroll
        for (int i = 0; i < 2; i++) gload16(gB[i] + kt + 32, lB[i] + nxt * 16384);
      }
      if (t < 14) {
        #pragma unroll
        for (int i = 0; i < 2; i++) {
          pa[cur][i][0] = *(const f32x4*)(gAs[i] + kt + 64);
          pa[cur][i][1] = *(const f32x4*)(gAs[i] + kt + 68);
        }
      }
      if (t == 0 || t == 14)
        asm volatile("s_waitcnt vmcnt(6) lgkmcnt(0)" ::: "memory");
      else if (t == 15)
        asm volatile("s_waitcnt vmcnt(0) lgkmcnt(0)" ::: "memory");
      else
        asm volatile("s_waitcnt vmcnt(10) lgkmcnt(0)" ::: "memory");
      __builtin_amdgcn_sched_barrier(0);
      __builtin_amdgcn_s_barrier();

      bf16x8 bv[4];
      #pragma unroll
      for (int nf = 0; nf < 4; nf++) {
        const int br = wc + nf * 16 + fr;
        bv[nf] = *(const bf16x8*)&Bs[cur][br][(fq ^ ((br >> 1) & 3)) * 8];
      }
      #pragma unroll
      for (int mf = 0; mf < 8; mf++) {
        const int ar = wr + mf * 16 + fr;
        bf16x8 av = *(const bf16x8*)&As[cur][ar][(fq ^ ((ar >> 1) & 3)) * 8];
        #pragma unroll
        for (int nf = 0; nf < 4; nf++)
          acc[mf][nf] = __builtin_amdgcn_mfma_f32_16x16x32_bf16(av, bv[nf], acc[mf][nf], 0, 0, 0);
      }

      if (t < 15) {
        #pragma unroll
        for (int i = 0; i < 2; i++)
          *(u16x8*)&As[nxt][arow_s[i]][aswz_s[i]] = cvt8(pa[nxt][i][0], pa[nxt][i][1]);
      }
      __builtin_amdgcn_s_barrier();
    }

    #pragma unroll
    for (int mf = 0; mf < 8; mf++)
      #pragma unroll
      for (int nf = 0; nf < 4; nf++)
        #pragma unroll
        for (int rr = 0; rr < 4; rr++) {
          const int m = m0 + wr + mf * 16 + fq * 4 + rr;
          const int n = n0 + wc + nf * 16 + fr;
          Y[(size_t)m * 512 + n] = f2bf(acc[mf][nf][rr]);
        }
  } else {
    const int c0 = bid - 256;
    const int m0 = (c0 & 3) * 128, n0 = ((c0 >> 2) & 3) * 256, b = c0 >> 4;
    const int wr = (wave >> 2) * 64, wc = (wave & 3) * 64;
    const unsigned short* wv = wb + 524288;

    unsigned short (*As)[128][32] = (unsigned short (*)[128][32])lds;
    unsigned short (*Bs)[256][32] = (unsigned short (*)[256][32])(lds + 8192);

    f32x4 acc[4][4] = {};

    const int ar_s = tid >> 2, aslot = tid & 3;
    const unsigned short* gA = wv + (size_t)(m0 + ar_s) * 512 + (aslot ^ ((ar_s >> 1) & 3)) * 8;
    char* lA = (char*)lds + tid * 16;

    int brow_s[2], bswz_s[2];
    const float* gBs[2];
    #pragma unroll
    for (int i = 0; i < 2; i++) {
      const int c = tid + 512 * i;
      brow_s[i] = c >> 2;
      bswz_s[i] = ((c & 3) ^ ((brow_s[i] >> 1) & 3)) * 8;
      gBs[i] = V + ((size_t)b * 1024 + n0 + brow_s[i]) * 512 + (c & 3) * 8;
    }

    f32x4 pb[2][2][2];
    #pragma unroll
    for (int i = 0; i < 2; i++) {
      pb[0][i][0] = *(const f32x4*)(gBs[i]);
      pb[0][i][1] = *(const f32x4*)(gBs[i] + 4);
      pb[1][i][0] = *(const f32x4*)(gBs[i] + 32);
      pb[1][i][1] = *(const f32x4*)(gBs[i] + 36);
    }
    gload16(gA, lA);
    #pragma unroll
    for (int i = 0; i < 2; i++)
      *(u16x8*)&Bs[0][brow_s[i]][bswz_s[i]] = cvt8(pb[0][i][0], pb[0][i][1]);

    #pragma unroll
    for (int t = 0; t < 16; t++) {
      const int cur = t & 1, nxt = cur ^ 1;
      const int kt = t * 32;
      if (t < 15) gload16(gA + kt + 32, lA + nxt * 8192);
      if (t < 14) {
        #pragma unroll
        for (int i = 0; i < 2; i++) {
          pb[cur][i][0] = *(const f32x4*)(gBs[i] + kt + 64);
          pb[cur][i][1] = *(const f32x4*)(gBs[i] + kt + 68);
        }
      }
      if (t == 0 || t == 14)
        asm volatile("s_waitcnt vmcnt(5) lgkmcnt(0)" ::: "memory");
      else if (t == 15)
        asm volatile("s_waitcnt vmcnt(0) lgkmcnt(0)" ::: "memory");
      else
        asm volatile("s_waitcnt vmcnt(9) lgkmcnt(0)" ::: "memory");
      __builtin_amdgcn_sched_barrier(0);
      __builtin_amdgcn_s_barrier();

      bf16x8 av[4], bv[4];
      #pragma unroll
      for (int mf = 0; mf < 4; mf++) {
        const int ar = wr + mf * 16 + fr;
        av[mf] = *(const bf16x8*)&As[cur][ar][(fq ^ ((ar >> 1) & 3)) * 8];
      }
      #pragma unroll
      for (int nf = 0; nf < 4; nf++) {
        const int br = wc + nf * 16 + fr;
        bv[nf] = *(const bf16x8*)&Bs[cur][br][(fq ^ ((br >> 1) & 3)) * 8];
      }
      #pragma unroll
      for (int mf = 0; mf < 4; mf++)
        #pragma unroll
        for (int nf = 0; nf < 4; nf++)
          acc[mf][nf] = __builtin_amdgcn_mfma_f32_16x16x32_bf16(av[mf], bv[nf], acc[mf][nf], 0, 0, 0);

      if (t < 15) {
        #pragma unroll
        for (int i = 0; i < 2; i++)
          *(u16x8*)&Bs[nxt][brow_s[i]][bswz_s[i]] = cvt8(pb[nxt][i][0], pb[nxt][i][1]);
      }
      __builtin_amdgcn_s_barrier();
    }

    #pragma unroll
    for (int mf = 0; mf < 4; mf++)
      #pragma unroll
      for (int nf = 0; nf < 4; nf++)
        #pragma unroll
        for (int rr = 0; rr < 4; rr++) {
          const int e = m0 + wr + mf * 16 + fq * 4 + rr;
          const int s = n0 + wc + nf * 16 + fr;
          vt[((size_t)b * 512 + e) * 1024 + s] = f2bf(acc[mf][nf][rr]);
        }
  }
}

// ---------------------------------------------------------------------------
// score_mv: blocks 0-255 = score256 (P'' + exp partials, unchanged inner
// loop); blocks 256-1279 = mvsum (8 rows/block @ 512 thr).
// Both roles consume only proj_all outputs — no intra-dispatch dependency.
// ---------------------------------------------------------------------------
__global__ __launch_bounds__(512, 2) void score_mv(
    const unsigned short* __restrict__ qb, const unsigned short* __restrict__ kb,
    const unsigned short* __restrict__ vt, const int* __restrict__ mask,
    unsigned short* __restrict__ P, float* __restrict__ partial,
    float* __restrict__ mvsum)
{
  __shared__ __align__(16) unsigned short As[2][256][32];
  __shared__ __align__(16) unsigned short Bs[2][256][32];

  const int bid = blockIdx.x;
  const int tid = threadIdx.x;

  if (bid >= 256) {
    // ---- mvsum: row = b*512+e, 8 rows per block ----
    const int row = (bid - 256) * 8 + (tid >> 6);
    const int b = row >> 9;
    const int lane = tid & 63;
    const unsigned short* vr = vt + (size_t)row * 1024 + lane * 16;
    const int* mr = mask + b * 1024 + lane * 16;
    u16x8 v0 = *(const u16x8*)(vr);
    u16x8 v1 = *(const u16x8*)(vr + 8);
    float s = 0.f;
    #pragma unroll
    for (int j = 0; j < 8; j++) {
      if (!mr[j])     s += bf2f(v0[j]);
      if (!mr[8 + j]) s += bf2f(v1[j]);
    }
    #pragma unroll
    for (int o = 32; o > 0; o >>= 1) s += __shfl_xor(s, o);
    if (lane == 0) mvsum[row] = s;
    return;
  }

  // ---- score256 role ----
  const int bz = bid >> 4;
  const int m0 = (bid & 3) * 256, n0 = ((bid >> 2) & 3) * 256;
  const int lane = tid & 63, wave = tid >> 6;
  const int wr = (wave >> 2) * 128, wc = (wave & 3) * 64;
  const int fr = lane & 15, fq = lane >> 4;

  f32x4 acc[8][4] = {};

  const unsigned short* gA[2]; char* lA[2];
  const unsigned short* gB[2]; char* lB[2];
  #pragma unroll
  for (int i = 0; i < 2; i++) {
    const int c = tid + 512 * i, row = c >> 2, slot = c & 3;
    const int sw = (slot ^ ((row >> 1) & 3)) * 8;
    gA[i] = qb + ((size_t)bz * 1024 + m0 + row) * 512 + sw;
    gB[i] = kb + ((size_t)bz * 1024 + n0 + row) * 512 + sw;
    lA[i] = (char*)&As[0][0][0] + c * 16;
    lB[i] = (char*)&Bs[0][0][0] + c * 16;
  }

  #pragma unroll
  for (int i = 0; i < 2; i++) { gload16(gA[i], lA[i]); gload16(gB[i], lB[i]); }

  int cur = 0;
  for (int kt = 0; kt < 512; kt += 32) {
    const int nb = cur ^ 1;
    if (kt < 480) {
      #pragma unroll
      for (int i = 0; i < 2; i++) {
        gload16(gA[i] + kt + 32, lA[i] + nb * 16384);
        gload16(gB[i] + kt + 32, lB[i] + nb * 16384);
      }
      asm volatile("s_waitcnt vmcnt(4) lgkmcnt(0)" ::: "memory");
    } else {
      asm volatile("s_waitcnt vmcnt(0) lgkmcnt(0)" ::: "memory");
    }
    __builtin_amdgcn_sched_barrier(0);
    __builtin_amdgcn_s_barrier();

    bf16x8 bv[4];
    #pragma unroll
    for (int nf = 0; nf < 4; nf++) {
      const int br = wc + nf * 16 + fr;
      bv[nf] = *(const bf16x8*)&Bs[cur][br][(fq ^ ((br >> 1) & 3)) * 8];
    }
    #pragma unroll
    for (int mf = 0; mf < 8; mf++) {
      const int ar = wr + mf * 16 + fr;
      bf16x8 av = *(const bf16x8*)&As[cur][ar][(fq ^ ((ar >> 1) & 3)) * 8];
      #pragma unroll
      for (int nf = 0; nf < 4; nf++)
        acc[mf][nf] = __builtin_amdgcn_mfma_f32_16x16x32_bf16(av, bv[nf], acc[mf][nf], 0, 0, 0);
    }
    __builtin_amdgcn_s_barrier();
    cur = nb;
  }

  int mcol[4];
  #pragma unroll
  for (int nf = 0; nf < 4; nf++)
    mcol[nf] = mask[bz * 1024 + n0 + wc + nf * 16 + fr];

  unsigned short* Pb = P + ((size_t)bz << 20);
  const int slot = ((bid >> 2) & 3) * 4 + (wave & 3);
  #pragma unroll
  for (int mf = 0; mf < 8; mf++) {
    #pragma unroll
    for (int rr = 0; rr < 4; rr++) {
      const int m = m0 + wr + mf * 16 + fq * 4 + rr;
      float e = 0.f;
      #pragma unroll
      for (int nf = 0; nf < 4; nf++) {
        const float ev = __expf(acc[mf][nf][rr] * SCALE_F);
        e += ev;
        Pb[(size_t)m * 1024 + n0 + wc + nf * 16 + fr] =
            mcol[nf] ? f2bf(ev) : (unsigned short)0;
      }
      e += __shfl_xor(e, 1); e += __shfl_xor(e, 2);
      e += __shfl_xor(e, 4); e += __shfl_xor(e, 8);
      if (fr == 0)
        partial[(size_t)slot * 16384 + bz * 1024 + m] = e;
    }
  }
}

// ---------------------------------------------------------------------------
// pv_attn: pure bf16 GEMM out = inv*(P''·vt^T) - 1e9*mvsum, WITH the final
// attn write fused into the K-loop: after each MFMA cluster, threads read
// their P'' values back from the staged As[cur] tile (LDS) and write
// attn = mask ? f32(P'')*inv : -1e9 for rows [m0,m0+64) x cols [kt,kt+32).
// Replaces the separate attn_write pass (saves 32 MB P reread + a dispatch).
// ---------------------------------------------------------------------------
__global__ __launch_bounds__(512) void pv_attn(
    const unsigned short* __restrict__ P, const unsigned short* __restrict__ vt,
    const float* __restrict__ partial, const float* __restrict__ mvsum,
    const int* __restrict__ mask,
    float* __restrict__ out, float* __restrict__ attn)
{
  __shared__ __align__(16) unsigned short As[2][64][32];   // 8 KB
  __shared__ __align__(16) unsigned short Bs[2][512][32];  // 64 KB
  __shared__ float inv_l[64];

  const int tid = threadIdx.x;
  const int bz = blockIdx.z, m0 = blockIdx.x * 64;
  const int lane = tid & 63, wave = tid >> 6;
  const int n0 = wave * 64;
  const int fr = lane & 15, fq = lane >> 4;

  f32x4 acc[4][4] = {};

  if (tid < 64) {
    float s = 0.f;
    #pragma unroll
    for (int p = 0; p < 16; p++) s += partial[(size_t)p * 16384 + bz * 1024 + m0 + tid];
    inv_l[tid] = 1.0f / s;
  }

  const unsigned short* gA = nullptr; char* lA = nullptr;
  if (tid < 256) {
    const int row = tid >> 2, slot = tid & 3;
    gA = P + ((size_t)bz << 20) + (size_t)(m0 + row) * 1024 + (slot ^ ((row >> 1) & 3)) * 8;
    lA = (char*)&As[0][0][0] + tid * 16;
  }
  const unsigned short* gB[4]; char* lB[4];
  #pragma unroll
  for (int i = 0; i < 4; i++) {
    const int c = tid + 512 * i, row = c >> 2, slot = c & 3;
    gB[i] = vt + ((size_t)bz * 512 + row) * 1024 + (slot ^ ((row >> 1) & 3)) * 8;
    lB[i] = (char*)&Bs[0][0][0] + c * 16;
  }

  // fused-attn-write geometry: this thread covers (arow, acol..acol+3)
  const int arow = tid >> 3, acol = (tid & 7) * 4;
  const int aslot8 = ((acol >> 3) ^ ((arow >> 1) & 3)) * 8 + (acol & 7);
  float* arp = attn + ((size_t)bz * 1024 + m0 + arow) * 1024 + acol;
  const int* mrp = mask + bz * 1024 + acol;

  if (tid < 256) gload16(gA, lA);
  #pragma unroll
  for (int i = 0; i < 4; i++) gload16(gB[i], lB[i]);
  __syncthreads();                       // inv_l ready (also first-tile wait below)

  int cur = 0;
  for (int t = 0; t < 32; t++) {
    const int nb = cur ^ 1;
    const int kt = t * 32;
    if (t < 31) {
      if (tid < 256) gload16(gA + kt + 32, lA + nb * 4096);
      #pragma unroll
      for (int i = 0; i < 4; i++) gload16(gB[i] + kt + 32, lB[i] + nb * 32768);
      if (wave < 4) asm volatile("s_waitcnt vmcnt(5) lgkmcnt(0)" ::: "memory");
      else          asm volatile("s_waitcnt vmcnt(4) lgkmcnt(0)" ::: "memory");
    } else {
      asm volatile("s_waitcnt vmcnt(0) lgkmcnt(0)" ::: "memory");
    }
    __builtin_amdgcn_sched_barrier(0);
    __builtin_amdgcn_s_barrier();

    bf16x8 af[4], bv[4];
    #pragma unroll
    for (int mf = 0; mf < 4; mf++) {
      const int ar = mf * 16 + fr;
      af[mf] = *(const bf16x8*)&As[cur][ar][(fq ^ ((ar >> 1) & 3)) * 8];
    }
    #pragma unroll
    for (int nf = 0; nf < 4; nf++) {
      const int br = n0 + nf * 16 + fr;
      bv[nf] = *(const bf16x8*)&Bs[cur][br][(fq ^ ((br >> 1) & 3)) * 8];
    }
    #pragma unroll
    for (int mf = 0; mf < 4; mf++)
      #pragma unroll
      for (int nf = 0; nf < 4; nf++)
        acc[mf][nf] = __builtin_amdgcn_mfma_f32_16x16x32_bf16(af[mf], bv[nf], acc[mf][nf], 0, 0, 0);

    // fused attn write for this K-slice (As[cur] stable until next barrier)
    {
      const u16x4 pv4 = *(const u16x4*)&As[cur][arow][aslot8];
      const i32x4 mv = *(const i32x4*)(mrp + kt);
      const float iv = inv_l[arow];
      f32x4 o;
      o[0] = mv[0] ? bf2f(pv4[0]) * iv : NEG_BIG_F;
      o[1] = mv[1] ? bf2f(pv4[1]) * iv : NEG_BIG_F;
      o[2] = mv[2] ? bf2f(pv4[2]) * iv : NEG_BIG_F;
      o[3] = mv[3] ? bf2f(pv4[3]) * iv : NEG_BIG_F;
      *(f32x4*)(arp + kt) = o;
    }
    __builtin_amdgcn_s_barrier();
    cur = nb;
  }

  float mvv[4];
  #pragma unroll
  for (int nf = 0; nf < 4; nf++)
    mvv[nf] = mvsum[bz * 512 + n0 + nf * 16 + fr];
  #pragma unroll
  for (int mf = 0; mf < 4; mf++)
    #pragma unroll
    for (int rr = 0; rr < 4; rr++) {
      const int m = m0 + mf * 16 + fq * 4 + rr;
      const float iv = inv_l[mf * 16 + fq * 4 + rr];
      #pragma unroll
      for (int nf = 0; nf < 4; nf++)
        out[((size_t)bz * 1024 + m) * 512 + n0 + nf * 16 + fr] =
            iv * acc[mf][nf][rr] + NEG_BIG_F * mvv[nf];
    }
}

// ---------------------------------------------------------------------------
extern "C" void kernel_launch(void* const* d_in, const int* in_sizes, int n_in,
                              void* d_out, int out_size, void* d_ws, size_t ws_size,
                              hipStream_t stream)
{
  const float* Q  = (const float*)d_in[0];
  const float* Kx = (const float*)d_in[1];
  const float* V  = (const float*)d_in[2];
  const float* WQ = (const float*)d_in[3];
  const float* WK = (const float*)d_in[4];
  const float* WV = (const float*)d_in[5];
  const int* mask = (const int*)d_in[6];

  const int B = 16, S = 1024, D = 512;
  float* out_f  = (float*)d_out;                      // B*S*D fp32 (final out)
  float* attn_f = out_f + (size_t)B * S * D;          // B*S*S fp32 (final attn)
  unsigned short* Pbuf = (unsigned short*)d_out;      // P'' bf16 aliases out region

  // ws: qb | kb | vt (8.39M ushorts each) | wb (0.79M) | partial | mvsum
  unsigned short* qb = (unsigned short*)d_ws;
  unsigned short* kb = qb + (size_t)B * S * D;
  unsigned short* vt = kb + (size_t)B * S * D;
  unsigned short* wb = vt + (size_t)B * S * D;
  float* partial = (float*)(wb + 786432);             // 16 x 16384 f32
  float* mvsum = partial + 262144;                    // 16 x 512 f32

  cvtW<<<dim3(128, 1, 3), 256, 0, stream>>>(WQ, WK, WV, wb);
  proj_all<<<dim3(512), 512, 0, stream>>>(Q, Kx, V, wb, qb, kb, vt);
  score_mv<<<dim3(1280), 512, 0, stream>>>(qb, kb, vt, mask, Pbuf, partial, mvsum);
  pv_attn<<<dim3(16, 1, 16), 512, 0, stream>>>(Pbuf, vt, partial, mvsum, mask, out_f, attn_f);
}